// Round 8
// baseline (1061.316 us; speedup 1.0000x reference)
//
#include <hip/hip_runtime.h>
#include <hip/hip_bf16.h>

// Round 8: fp32 in / fp32 out (verified R7). Attention rewritten with
// transposed scores (S^T = K·Q^T): softmax reductions become in-lane,
// P feeds PV directly via a permuted-k contraction — no LDS, no barriers.

#define S_LEN 2048

typedef __hip_bfloat16 bf16;
using bf16x8 = __attribute__((ext_vector_type(8))) __bf16;
using bf16x4 = __attribute__((ext_vector_type(4))) __bf16;
using f32x4  = __attribute__((ext_vector_type(4))) float;

__device__ inline unsigned short bf16_bits(float f) {
    union { __hip_bfloat16 h; unsigned short u; } cv;
    cv.h = __float2bfloat16(f);
    return cv.u;
}

// load 8 consecutive fp32, convert RNE to a bf16x8 fragment
__device__ inline bf16x8 load_cvt8(const float* __restrict__ p) {
    f32x4 a = *(const f32x4*)p;
    f32x4 b = *(const f32x4*)(p + 4);
    union { bf16x8 v; unsigned short u[8]; } r;
    r.u[0] = bf16_bits(a[0]); r.u[1] = bf16_bits(a[1]);
    r.u[2] = bf16_bits(a[2]); r.u[3] = bf16_bits(a[3]);
    r.u[4] = bf16_bits(b[0]); r.u[5] = bf16_bits(b[1]);
    r.u[6] = bf16_bits(b[2]); r.u[7] = bf16_bits(b[3]);
    return r.v;
}

// ---------------- weight transpose + fp32->bf16: out[n][k] = (bf16)in[k][n] ----
__global__ __launch_bounds__(256) void transpose_k(const float* __restrict__ in,
                                                   bf16* __restrict__ out,
                                                   int R, int C) {
    __shared__ float tile[32][33];
    int tx = threadIdx.x & 31, ty = threadIdx.x >> 5;
    int r0 = blockIdx.y * 32, c0 = blockIdx.x * 32;
#pragma unroll
    for (int p = 0; p < 4; ++p)
        tile[ty + p * 8][tx] = in[(size_t)(r0 + ty + p * 8) * C + c0 + tx];
    __syncthreads();
#pragma unroll
    for (int p = 0; p < 4; ++p)
        out[(size_t)(c0 + ty + p * 8) * R + r0 + tx] = __float2bfloat16(tile[tx][ty + p * 8]);
}

// ---------------- GEMM: C = A[M,K] * Bt[N,K]^T (bf16 MFMA, fp32 acc)
// a_fp32: A fp32 (converted during staging) else bf16.
// mode 0: bf16 C (scaled). mode 1: V-transpose epilogue Vt[b][hkv][d][s]. mode 2: fp32 C.
__global__ __launch_bounds__(256) void gemm_k(const void* __restrict__ Av,
                                              const bf16* __restrict__ Bt,
                                              void* __restrict__ Cv,
                                              int M, int N, int K, int mode, int a_fp32,
                                              float cscale) {
    __shared__ bf16 As[128 * 40];
    __shared__ bf16 Bs[128 * 40];
    int tid  = threadIdx.x;
    int lane = tid & 63, wave = tid >> 6;
    int quad = lane >> 4, r = lane & 15;
    int wm = (wave >> 1) * 64, wn = (wave & 1) * 64;
    int m0 = blockIdx.y * 128, n0 = blockIdx.x * 128;

    f32x4 acc[4][4];
#pragma unroll
    for (int i = 0; i < 4; ++i)
#pragma unroll
        for (int j = 0; j < 4; ++j) acc[i][j] = (f32x4)0.0f;

    int srow = tid >> 2;
    int skc  = (tid & 3) << 3;

    const float* Af = (const float*)Av;
    const bf16*  Ab = (const bf16*)Av;

    for (int k0 = 0; k0 < K; k0 += 32) {
        __syncthreads();
        if (a_fp32) {
            *(bf16x8*)&As[srow * 40 + skc]        = load_cvt8(Af + (size_t)(m0 + srow) * K + k0 + skc);
            *(bf16x8*)&As[(srow + 64) * 40 + skc] = load_cvt8(Af + (size_t)(m0 + srow + 64) * K + k0 + skc);
        } else {
            *(bf16x8*)&As[srow * 40 + skc]        = *(const bf16x8*)(Ab + (size_t)(m0 + srow) * K + k0 + skc);
            *(bf16x8*)&As[(srow + 64) * 40 + skc] = *(const bf16x8*)(Ab + (size_t)(m0 + srow + 64) * K + k0 + skc);
        }
        *(bf16x8*)&Bs[srow * 40 + skc]        = *(const bf16x8*)(Bt + (size_t)(n0 + srow) * K + k0 + skc);
        *(bf16x8*)&Bs[(srow + 64) * 40 + skc] = *(const bf16x8*)(Bt + (size_t)(n0 + srow + 64) * K + k0 + skc);
        __syncthreads();
        bf16x8 af[4], bfr[4];
#pragma unroll
        for (int mt = 0; mt < 4; ++mt) af[mt]  = *(const bf16x8*)&As[(wm + mt * 16 + r) * 40 + quad * 8];
#pragma unroll
        for (int nt = 0; nt < 4; ++nt) bfr[nt] = *(const bf16x8*)&Bs[(wn + nt * 16 + r) * 40 + quad * 8];
#pragma unroll
        for (int mt = 0; mt < 4; ++mt)
#pragma unroll
            for (int nt = 0; nt < 4; ++nt)
                acc[mt][nt] = __builtin_amdgcn_mfma_f32_16x16x32_bf16(af[mt], bfr[nt], acc[mt][nt], 0, 0, 0);
    }

    if (mode == 0) {
        bf16* C = (bf16*)Cv;
#pragma unroll
        for (int mt = 0; mt < 4; ++mt)
#pragma unroll
            for (int nt = 0; nt < 4; ++nt) {
                int row = m0 + wm + mt * 16 + quad * 4;
                int col = n0 + wn + nt * 16 + r;
#pragma unroll
                for (int i = 0; i < 4; ++i)
                    C[(size_t)(row + i) * N + col] = __float2bfloat16(acc[mt][nt][i] * cscale);
            }
    } else if (mode == 1) {
        unsigned short* C = (unsigned short*)Cv;
#pragma unroll
        for (int mt = 0; mt < 4; ++mt)
#pragma unroll
            for (int nt = 0; nt < 4; ++nt) {
                int rowb = m0 + wm + mt * 16 + quad * 4;
                int col  = n0 + wn + nt * 16 + r;
                int b = rowb >> 11, s = rowb & 2047;
                ushort4 pk;
                pk.x = bf16_bits(acc[mt][nt][0]);
                pk.y = bf16_bits(acc[mt][nt][1]);
                pk.z = bf16_bits(acc[mt][nt][2]);
                pk.w = bf16_bits(acc[mt][nt][3]);
                *(ushort4*)(C + (size_t)(b * 512 + col) * 2048 + s) = pk;
            }
    } else {
        float* C = (float*)Cv;
#pragma unroll
        for (int mt = 0; mt < 4; ++mt)
#pragma unroll
            for (int nt = 0; nt < 4; ++nt) {
                int row = m0 + wm + mt * 16 + quad * 4;
                int col = n0 + wn + nt * 16 + r;
#pragma unroll
                for (int i = 0; i < 4; ++i)
                    C[(size_t)(row + i) * N + col] = acc[mt][nt][i];
            }
    }
}

// ---------------- flash attention (GQA), transposed-S formulation --------------
// Qin: [B,S,2048] bf16 (h*64+d), PRE-SCALED by 1/8. K: [B,S,512] bf16.
// Vt: [B][8][64][S] bf16.  Aout: [B,S,2048] bf16.
// One block = 4 waves; wave w owns q-rows q0..q0+15 (q = lane&15).
// S^T = K·Q^T: lane (quad,r) holds tokens {quad*4+i} (tile0) and {16+quad*4+i}
// (tile1) of q-row r — token reductions are in-lane + 2 shuffles.
// PV uses permuted contraction k: token(quad*8+j) = j<4 ? quad*4+j : 16+quad*4+(j-4),
// so the B-fragment is the lane-local p values (no LDS round-trip) and the
// A-fragment is two contiguous 8B reads of Vt.
__global__ __launch_bounds__(256) void attn_k(const bf16* __restrict__ Qin,
                                              const bf16* __restrict__ Kb,
                                              const bf16* __restrict__ Vt,
                                              bf16* __restrict__ Aout) {
    int tid = threadIdx.x, lane = tid & 63, w = tid >> 6;
    int quad = lane >> 4, r = lane & 15;
    int qt = blockIdx.x, h = blockIdx.y, b = blockIdx.z;
    int hk = h >> 2;
    int q0 = qt * 64 + w * 16;

    bf16x8 qf[2];
#pragma unroll
    for (int f = 0; f < 2; ++f)
        qf[f] = *(const bf16x8*)(Qin + (size_t)(b * S_LEN + q0 + r) * 2048 + h * 64 + f * 32 + quad * 8);

    const bf16* Kbase = Kb + (size_t)b * S_LEN * 512 + hk * 64;
    const bf16* Vbase = Vt + (size_t)(b * 512 + hk * 64) * 2048;

    f32x4 oacc[4];
#pragma unroll
    for (int dt = 0; dt < 4; ++dt) oacc[dt] = (f32x4)0.0f;
    float m_i = -INFINITY, l_i = 0.0f;

    for (int k0 = 0; k0 < S_LEN; k0 += 32) {
        // S^T tiles: s0 = tokens k0+quad*4+i, s1 = tokens k0+16+quad*4+i, q-col = r
        f32x4 s0 = (f32x4)0.0f, s1 = (f32x4)0.0f;
        bf16x8 kf0 = *(const bf16x8*)(Kbase + (size_t)(k0 + r) * 512 + quad * 8);
        bf16x8 kf1 = *(const bf16x8*)(Kbase + (size_t)(k0 + r) * 512 + 32 + quad * 8);
        bf16x8 kf2 = *(const bf16x8*)(Kbase + (size_t)(k0 + 16 + r) * 512 + quad * 8);
        bf16x8 kf3 = *(const bf16x8*)(Kbase + (size_t)(k0 + 16 + r) * 512 + 32 + quad * 8);
        s0 = __builtin_amdgcn_mfma_f32_16x16x32_bf16(kf0, qf[0], s0, 0, 0, 0);
        s0 = __builtin_amdgcn_mfma_f32_16x16x32_bf16(kf1, qf[1], s0, 0, 0, 0);
        s1 = __builtin_amdgcn_mfma_f32_16x16x32_bf16(kf2, qf[0], s1, 0, 0, 0);
        s1 = __builtin_amdgcn_mfma_f32_16x16x32_bf16(kf3, qf[1], s1, 0, 0, 0);

        // online softmax over 32 tokens (all values in this lane belong to q-row r)
        float tmax = fmaxf(fmaxf(fmaxf(s0[0], s0[1]), fmaxf(s0[2], s0[3])),
                           fmaxf(fmaxf(s1[0], s1[1]), fmaxf(s1[2], s1[3])));
        tmax = fmaxf(tmax, __shfl_xor(tmax, 16));
        tmax = fmaxf(tmax, __shfl_xor(tmax, 32));
        float mnew  = fmaxf(m_i, tmax);
        float alpha = __expf(m_i - mnew);
        float p0[4], p1[4], ps = 0.0f;
#pragma unroll
        for (int i = 0; i < 4; ++i) { p0[i] = __expf(s0[i] - mnew); ps += p0[i]; }
#pragma unroll
        for (int i = 0; i < 4; ++i) { p1[i] = __expf(s1[i] - mnew); ps += p1[i]; }
        ps += __shfl_xor(ps, 16);
        ps += __shfl_xor(ps, 32);
        l_i = l_i * alpha + ps;
        m_i = mnew;

        // PV B-fragment: lane-local p in permuted-k order
        union { bf16x8 v; unsigned short u[8]; } pf;
#pragma unroll
        for (int i = 0; i < 4; ++i) { pf.u[i] = bf16_bits(p0[i]); pf.u[4 + i] = bf16_bits(p1[i]); }

#pragma unroll
        for (int dt = 0; dt < 4; ++dt) {
            const bf16* vrow = Vbase + (size_t)(dt * 16 + r) * 2048 + k0 + quad * 4;
            union { bf16x8 v; bf16x4 h[2]; } vf;
            vf.h[0] = *(const bf16x4*)vrow;         // tokens k0+quad*4 .. +3
            vf.h[1] = *(const bf16x4*)(vrow + 16);  // tokens k0+16+quad*4 .. +3
            f32x4 o = oacc[dt];
#pragma unroll
            for (int i = 0; i < 4; ++i) o[i] *= alpha;
            oacc[dt] = __builtin_amdgcn_mfma_f32_16x16x32_bf16(vf.v, pf.v, o, 0, 0, 0);
        }
    }

    // oacc[dt][i] = out^T[d = dt*16 + quad*4 + i][q = r]
    float inv = 1.0f / l_i;
#pragma unroll
    for (int dt = 0; dt < 4; ++dt) {
        ushort4 pk;
        pk.x = bf16_bits(oacc[dt][0] * inv);
        pk.y = bf16_bits(oacc[dt][1] * inv);
        pk.z = bf16_bits(oacc[dt][2] * inv);
        pk.w = bf16_bits(oacc[dt][3] * inv);
        *(ushort4*)((unsigned short*)Aout +
                    (size_t)(b * S_LEN + q0 + r) * 2048 + h * 64 + dt * 16 + quad * 4) = pk;
    }
}

extern "C" void kernel_launch(void* const* d_in, const int* in_sizes, int n_in,
                              void* d_out, int out_size, void* d_ws, size_t ws_size,
                              hipStream_t stream) {
    const float* x  = (const float*)d_in[0];
    const float* wq = (const float*)d_in[1];
    const float* wk = (const float*)d_in[2];
    const float* wv = (const float*)d_in[3];
    const float* wo = (const float*)d_in[4];
    char* ws = (char*)d_ws;

    // d_out (32 MB fp32): first half parks bf16 Q; final GEMM overwrites all.
    // ws (24 MB, phased):
    //   phase 1: [0,8M)=wqT [8,10M)=wkT [10,12M)=wvT
    //   phase 2: [0,16M)=attnOut(bf16)  [16,20M)=Kb  [20,24M)=Vt
    //   phase 3: [0,16M)=attnOut        [16,24M)=woT
    bf16* wqT  = (bf16*)(ws + 0);
    bf16* wkT  = (bf16*)(ws + 8388608);
    bf16* wvT  = (bf16*)(ws + 10485760);
    bf16* attn = (bf16*)(ws + 0);
    bf16* Kb   = (bf16*)(ws + 16777216);
    bf16* Vtb  = (bf16*)(ws + 20971520);
    bf16* woT  = (bf16*)(ws + 16777216);
    bf16* Qb   = (bf16*)d_out;

    transpose_k<<<dim3(64, 64), 256, 0, stream>>>(wq, wqT, 2048, 2048);
    transpose_k<<<dim3(16, 64), 256, 0, stream>>>(wk, wkT, 2048, 512);
    transpose_k<<<dim3(16, 64), 256, 0, stream>>>(wv, wvT, 2048, 512);

    // Q pre-scaled by 1/sqrt(64) in the epilogue
    gemm_k<<<dim3(16, 32), 256, 0, stream>>>(x, wqT, Qb, 4096, 2048, 2048, 0, 1, 0.125f);
    gemm_k<<<dim3(4, 32), 256, 0, stream>>>(x, wkT, Kb, 4096, 512, 2048, 0, 1, 1.0f);
    gemm_k<<<dim3(4, 32), 256, 0, stream>>>(x, wvT, Vtb, 4096, 512, 2048, 1, 1, 1.0f);

    attn_k<<<dim3(32, 32, 2), 256, 0, stream>>>(Qb, Kb, Vtb, attn);

    transpose_k<<<dim3(64, 64), 256, 0, stream>>>(wo, woT, 2048, 2048);

    gemm_k<<<dim3(16, 32), 256, 0, stream>>>(attn, woT, d_out, 4096, 2048, 2048, 2, 0, 1.0f);
}